// Round 5
// baseline (269.370 us; speedup 1.0000x reference)
//
#include <hip/hip_runtime.h>
#include <stdint.h>

#define EPS_NORM 1e-12f
#define F32_TINY 1.17549435e-38f

static __device__ __forceinline__ int rfl(int v) {
  return __builtin_amdgcn_readfirstlane(v);
}

// ---------------- Threefry2x32 (exact JAX replica, 20 rounds) ----------------
__device__ __forceinline__ void threefry2x32(uint32_t k0, uint32_t k1,
                                             uint32_t x0, uint32_t x1,
                                             uint32_t& o0, uint32_t& o1) {
  uint32_t ks2 = k0 ^ k1 ^ 0x1BD11BDAu;
  x0 += k0; x1 += k1;
#define TF_ROT(r) { x0 += x1; x1 = (x1 << (r)) | (x1 >> (32 - (r))); x1 ^= x0; }
  TF_ROT(13) TF_ROT(15) TF_ROT(26) TF_ROT(6)
  x0 += k1; x1 += ks2 + 1u;
  TF_ROT(17) TF_ROT(29) TF_ROT(16) TF_ROT(24)
  x0 += ks2; x1 += k0 + 2u;
  TF_ROT(13) TF_ROT(15) TF_ROT(26) TF_ROT(6)
  x0 += k0; x1 += k1 + 3u;
  TF_ROT(17) TF_ROT(29) TF_ROT(16) TF_ROT(24)
  x0 += k1; x1 += ks2 + 4u;
  TF_ROT(13) TF_ROT(15) TF_ROT(26) TF_ROT(6)
  x0 += ks2; x1 += k0 + 5u;
#undef TF_ROT
  o0 = x0; o1 = x1;
}

// ================= PHASE 1 mega-kernel: T1 + T2c/Eg + init + ui ==============
// Roles by blockIdx (256 thr each):
//   [0,782)      T1:  4 waves/blk, wave w=blk*4+wv (<3125), 64 rows/wave,
//                     lane=col, 4 rows/pass, W1 staged in LDS.
//   [782,807)    T2c: same but srow=allc[row], W2 staged; also raw copy -> Eg.
//   [807,1063)   init: kg -> out0(float) + wkg2(int), grid-stride int4.
//   [1063,2087)  ui:  wave per item b, lane=col, uiW per-lane VMEM.
__global__ __launch_bounds__(256) void k_phase1(
    const float* __restrict__ E, const int* __restrict__ allc,
    const float* __restrict__ W1, const float* __restrict__ b1,
    const float* __restrict__ W2, const float* __restrict__ b2,
    const float* __restrict__ U, const int* __restrict__ users,
    const float* __restrict__ Iemb, const float* __restrict__ uiW,
    const float* __restrict__ uib, const int* __restrict__ kg,
    float* __restrict__ T1, float* __restrict__ T2c, float* __restrict__ Eg,
    float* __restrict__ uiE, float* __restrict__ out0, int* __restrict__ wkg2) {
  __shared__ float Wl[4096];
  const int blk = blockIdx.x, tid = threadIdx.x;
  const int wv = tid >> 6, lane = tid & 63;
  if (blk < 807) {  // ---------------- transform roles ----------------
    const bool isT1 = blk < 782;
    const float* W = isT1 ? W1 : W2;
    const float* bias = isT1 ? b1 : b2;
    for (int i = tid; i < 4096; i += 256) Wl[i] = W[i];
    __syncthreads();
    int w = isT1 ? blk * 4 + wv : (blk - 782) * 4 + wv;
    if (isT1 && w >= 3125) return;
    float bl = bias[lane];
    float* dst = isT1 ? T1 : T2c;
    const int rbase = w * 64;
#pragma unroll 1
    for (int pass = 0; pass < 16; ++pass) {
      int r0 = rbase + pass * 4;
      int sr0, sr1, sr2, sr3;
      if (isT1) { sr0 = r0; sr1 = r0 + 1; sr2 = r0 + 2; sr3 = r0 + 3; }
      else {
        sr0 = rfl(allc[r0]);     sr1 = rfl(allc[r0 + 1]);
        sr2 = rfl(allc[r0 + 2]); sr3 = rfl(allc[r0 + 3]);
      }
      const float* e0 = E + (size_t)sr0 * 64;
      const float* e1 = E + (size_t)sr1 * 64;
      const float* e2 = E + (size_t)sr2 * 64;
      const float* e3 = E + (size_t)sr3 * 64;
      float y0 = 0.f, y1 = 0.f, y2 = 0.f, y3 = 0.f;
#pragma unroll
      for (int k = 0; k < 64; ++k) {
        float wk = Wl[k * 64 + lane];       // ds_read_b32, 2-way alias (free)
        y0 = fmaf(e0[k], wk, y0);
        y1 = fmaf(e1[k], wk, y1);
        y2 = fmaf(e2[k], wk, y2);
        y3 = fmaf(e3[k], wk, y3);
      }
      y0 += bl; y1 += bl; y2 += bl; y3 += bl;
      float ys[4] = {y0, y1, y2, y3};
#pragma unroll
      for (int q = 0; q < 4; ++q) {
        float y = ys[q];
        float ss = y * y;
#pragma unroll
        for (int off = 32; off; off >>= 1) ss += __shfl_xor(ss, off);
        float yn = y / fmaxf(sqrtf(ss), EPS_NORM);
        dst[(size_t)(r0 + q) * 64 + lane] = yn;   // coalesced dword store
      }
      if (!isT1) {  // raw candidate-row copy for k_score2e (bitwise copy)
        Eg[(size_t)r0 * 64 + lane]       = e0[lane];
        Eg[(size_t)(r0 + 1) * 64 + lane] = e1[lane];
        Eg[(size_t)(r0 + 2) * 64 + lane] = e2[lane];
        Eg[(size_t)(r0 + 3) * 64 + lane] = e3[lane];
      }
    }
  } else if (blk < 1063) {  // ---------------- init role ----------------
    int ib = blk - 807;
    const int4* kg4 = reinterpret_cast<const int4*>(kg);
    float4* o4 = reinterpret_cast<float4*>(out0);
    int4* w4 = reinterpret_cast<int4*>(wkg2);
    for (int i = ib * 256 + tid; i < 800000; i += 256 * 256) {
      int4 v = kg4[i];
      o4[i] = make_float4((float)v.x, (float)v.y, (float)v.z, (float)v.w);
      w4[i] = v;
    }
  } else {  // ---------------- ui role ----------------
    int b = (blk - 1063) * 4 + wv;
    int usr = rfl(users[b]);
    const float* ur = U + (size_t)usr * 64;
    const float* ir = Iemb + (size_t)b * 64;
    float y = 0.f;
#pragma unroll
    for (int k = 0; k < 64; ++k) y = fmaf(ur[k], uiW[k * 64 + lane], y);
#pragma unroll
    for (int k = 0; k < 64; ++k) y = fmaf(ir[k], uiW[(64 + k) * 64 + lane], y);
    y += uib[lane];
    float ss = y * y;
#pragma unroll
    for (int off = 32; off; off >>= 1) ss += __shfl_xor(ss, off);
    float yn = y / fmaxf(sqrtf(ss), EPS_NORM);
    uiE[(size_t)b * 64 + lane] = yn;
  }
}

// ================= fallback-path kernels (unchanged from R4) =================
__global__ __launch_bounds__(256) void k_init(const int* __restrict__ kg,
                                              float* __restrict__ out0,
                                              int* __restrict__ wkg2, int n) {
  int i = blockIdx.x * 256 + threadIdx.x;
  if (i < n) { int v = kg[i]; out0[i] = (float)v; wkg2[i] = v; }
}

__device__ __forceinline__ void transform_row(const float4* __restrict__ Er,
                                              const float* __restrict__ W,
                                              const float* __restrict__ bias,
                                              float (&yn)[64]) {
  float y[64];
#pragma unroll
  for (int j = 0; j < 64; ++j) y[j] = 0.f;
  float4 c0 = Er[0], c1 = Er[1], c2 = Er[2], c3 = Er[3];
#pragma unroll 1
  for (int cc = 0; cc < 4; ++cc) {
    float4 n0, n1, n2, n3;
    if (cc < 3) { n0 = Er[cc * 4 + 4]; n1 = Er[cc * 4 + 5];
                  n2 = Er[cc * 4 + 6]; n3 = Er[cc * 4 + 7]; }
    float ev[16] = {c0.x, c0.y, c0.z, c0.w, c1.x, c1.y, c1.z, c1.w,
                    c2.x, c2.y, c2.z, c2.w, c3.x, c3.y, c3.z, c3.w};
#pragma unroll
    for (int k2i = 0; k2i < 16; ++k2i) {
      const float4* Wr = reinterpret_cast<const float4*>(
          W + ((size_t)(cc * 16 + k2i)) * 64);
      float ek = ev[k2i];
#pragma unroll
      for (int j4 = 0; j4 < 16; ++j4) {
        float4 w = Wr[j4];
        y[j4 * 4 + 0] = fmaf(ek, w.x, y[j4 * 4 + 0]);
        y[j4 * 4 + 1] = fmaf(ek, w.y, y[j4 * 4 + 1]);
        y[j4 * 4 + 2] = fmaf(ek, w.z, y[j4 * 4 + 2]);
        y[j4 * 4 + 3] = fmaf(ek, w.w, y[j4 * 4 + 3]);
      }
    }
    c0 = n0; c1 = n1; c2 = n2; c3 = n3;
  }
  const float4* B4 = reinterpret_cast<const float4*>(bias);
#pragma unroll
  for (int j4 = 0; j4 < 16; ++j4) {
    float4 bb = B4[j4];
    float bv[4] = {bb.x, bb.y, bb.z, bb.w};
#pragma unroll
    for (int t = 0; t < 4; ++t) y[j4 * 4 + t] = __fadd_rn(y[j4 * 4 + t], bv[t]);
  }
  float S1[32];
#pragma unroll
  for (int i = 0; i < 32; ++i)
    S1[i] = __fadd_rn(__fmul_rn(y[i], y[i]), __fmul_rn(y[i + 32], y[i + 32]));
#pragma unroll
  for (int i = 0; i < 16; ++i) S1[i] = __fadd_rn(S1[i], S1[i + 16]);
#pragma unroll
  for (int i = 0; i < 8; ++i)  S1[i] = __fadd_rn(S1[i], S1[i + 8]);
#pragma unroll
  for (int i = 0; i < 4; ++i)  S1[i] = __fadd_rn(S1[i], S1[i + 4]);
#pragma unroll
  for (int i = 0; i < 2; ++i)  S1[i] = __fadd_rn(S1[i], S1[i + 2]);
  float ss = __fadd_rn(S1[0], S1[1]);
  float denom = fmaxf(sqrtf(ss), EPS_NORM);
#pragma unroll
  for (int j = 0; j < 64; ++j) yn[j] = y[j] / denom;
}

__global__ __launch_bounds__(256) void k_transform64(
    const float* __restrict__ src, const int* __restrict__ gidx,
    const float* __restrict__ W, const float* __restrict__ bias,
    float* __restrict__ out, int nrows) {
  __shared__ float Wl[4096];
  for (int i = threadIdx.x; i < 4096; i += 256) Wl[i] = W[i];
  __syncthreads();
  int wid = threadIdx.x >> 6, lane = threadIdx.x & 63;
  int row = rfl(blockIdx.x * 4 + wid);
  if (row >= nrows) return;
  int srow = rfl(gidx ? gidx[row] : row);
  const float* er = src + (size_t)srow * 64;
  float y = 0.f;
#pragma unroll
  for (int k = 0; k < 64; ++k) y = fmaf(er[k], Wl[k * 64 + lane], y);
  y += bias[lane];
  float ss = y * y;
#pragma unroll
  for (int off = 32; off; off >>= 1) ss += __shfl_xor(ss, off);
  float yn = y / fmaxf(sqrtf(ss), EPS_NORM);
  out[(size_t)row * 64 + lane] = yn;
}

__global__ __launch_bounds__(256) void k_ui(
    const float* __restrict__ U, const int* __restrict__ users,
    const float* __restrict__ Iemb, const float* __restrict__ W,
    const float* __restrict__ bias, float* __restrict__ out, int B) {
  __shared__ float Wl[8192];
  for (int i = threadIdx.x; i < 8192; i += 256) Wl[i] = W[i];
  __syncthreads();
  int wid = threadIdx.x >> 6, lane = threadIdx.x & 63;
  int b = rfl(blockIdx.x * 4 + wid);
  if (b >= B) return;
  int usr = rfl(users[b]);
  const float* ur = U + (size_t)usr * 64;
  const float* ir = Iemb + (size_t)b * 64;
  float y = 0.f;
#pragma unroll
  for (int k = 0; k < 64; ++k) y = fmaf(ur[k], Wl[k * 64 + lane], y);
#pragma unroll
  for (int k = 0; k < 64; ++k) y = fmaf(ir[k], Wl[(64 + k) * 64 + lane], y);
  y += bias[lane];
  float ss = y * y;
#pragma unroll
  for (int off = 32; off; off >>= 1) ss += __shfl_xor(ss, off);
  float yn = y / fmaxf(sqrtf(ss), EPS_NORM);
  out[(size_t)b * 64 + lane] = yn;
}

// ------------------ step1 tail (softmax + top4), shared ----------------------
__device__ __forceinline__ void score1_tail(
    float s, int lane, int b, int item, int nb,
    const int* __restrict__ nrel,
    float* __restrict__ out0, float* __restrict__ ap1_out,
    int* __restrict__ s1_idx, int* __restrict__ s1_rel, int* __restrict__ s1_ent,
    float* __restrict__ lmp1) {
  float m = s;
#pragma unroll
  for (int off = 32; off; off >>= 1) m = fmaxf(m, __shfl_xor(m, off));
  float ex = expf(s - m);
  float sum = ex;
#pragma unroll
  for (int off = 32; off; off >>= 1) sum += __shfl_xor(sum, off);
  float p = ex / sum;
  int rank = 0;
  for (int k2 = 0; k2 < 64; ++k2) {
    float pv = __shfl(p, k2);
    rank += (pv > p || (pv == p && k2 < lane)) ? 1 : 0;
  }
  float acc = 0.f;
#pragma unroll
  for (int rr = 0; rr < 4; ++rr) {
    unsigned long long msk = __ballot(rank == rr);
    int src = __ffsll(msk) - 1;
    acc += __shfl(p, src);
  }
  float lm = logf(acc * 0.25f);
  if (lane == 0) { ap1_out[b] = lm; lmp1[b] = lm; }
  if (rank < 4) {
    s1_idx[b * 4 + rank] = lane;
    s1_ent[b * 4 + rank] = nb;
    s1_rel[b * 4 + rank] = nrel[(size_t)item * 64 + lane];
    out0[(size_t)item * 64 + lane] = 0.0f;
  }
}

// ---------- step1 (path A): gather T1 rows + in-register dot + tail ----------
__global__ __launch_bounds__(256) void k_score1g(
    const int* __restrict__ items, const int* __restrict__ kg,
    const int* __restrict__ nrel, const float* __restrict__ T1,
    const float* __restrict__ uiE,
    float* __restrict__ out0, float* __restrict__ ap1_out,
    int* __restrict__ s1_idx, int* __restrict__ s1_rel, int* __restrict__ s1_ent,
    float* __restrict__ lmp1) {
  int tid = threadIdx.x, wv = tid >> 6, lane = tid & 63;
  int b = rfl(blockIdx.x * 4 + wv);
  int item = rfl(items[b]);
  int nb = kg[(size_t)item * 64 + lane];
  const float4* R = reinterpret_cast<const float4*>(T1 + (size_t)nb * 64);
  float yn[64];
#pragma unroll
  for (int j4 = 0; j4 < 16; ++j4) {
    float4 v = R[j4];
    yn[4 * j4] = v.x; yn[4 * j4 + 1] = v.y; yn[4 * j4 + 2] = v.z; yn[4 * j4 + 3] = v.w;
  }
  const float4* Ur = reinterpret_cast<const float4*>(uiE + (size_t)b * 64);
  float D[32];
#pragma unroll
  for (int i4 = 0; i4 < 8; ++i4) {
    float4 ua = Ur[i4], ub = Ur[i4 + 8];
    float uav[4] = {ua.x, ua.y, ua.z, ua.w};
    float ubv[4] = {ub.x, ub.y, ub.z, ub.w};
#pragma unroll
    for (int t = 0; t < 4; ++t) {
      int i = i4 * 4 + t;
      D[i] = __fadd_rn(__fmul_rn(yn[i], uav[t]), __fmul_rn(yn[i + 32], ubv[t]));
    }
  }
#pragma unroll
  for (int i = 0; i < 16; ++i) D[i] = __fadd_rn(D[i], D[i + 16]);
#pragma unroll
  for (int i = 0; i < 8; ++i)  D[i] = __fadd_rn(D[i], D[i + 8]);
#pragma unroll
  for (int i = 0; i < 4; ++i)  D[i] = __fadd_rn(D[i], D[i + 4]);
#pragma unroll
  for (int i = 0; i < 2; ++i)  D[i] = __fadd_rn(D[i], D[i + 2]);
  float s = __fadd_rn(D[0], D[1]);
  score1_tail(s, lane, b, item, nb, nrel, out0, ap1_out, s1_idx, s1_rel, s1_ent, lmp1);
}

// ---------- step1 (path B fallback): fused transform + dot + tail ------------
__global__ __launch_bounds__(256) void k_score1(
    const int* __restrict__ items, const int* __restrict__ kg,
    const int* __restrict__ nrel, const float* __restrict__ E,
    const float* __restrict__ W1, const float* __restrict__ b1,
    const float* __restrict__ uiE,
    float* __restrict__ out0, float* __restrict__ ap1_out,
    int* __restrict__ s1_idx, int* __restrict__ s1_rel, int* __restrict__ s1_ent,
    float* __restrict__ lmp1) {
  int tid = threadIdx.x, wv = tid >> 6, lane = tid & 63;
  int b = rfl(blockIdx.x * 4 + wv);
  int item = rfl(items[b]);
  int nb = kg[(size_t)item * 64 + lane];
  const float4* Er = reinterpret_cast<const float4*>(E + (size_t)nb * 64);
  float yn[64];
  transform_row(Er, W1, b1, yn);
  const float4* Ur = reinterpret_cast<const float4*>(uiE + (size_t)b * 64);
  float D[32];
#pragma unroll
  for (int i4 = 0; i4 < 8; ++i4) {
    float4 ua = Ur[i4], ub = Ur[i4 + 8];
    float uav[4] = {ua.x, ua.y, ua.z, ua.w};
    float ubv[4] = {ub.x, ub.y, ub.z, ub.w};
#pragma unroll
    for (int t = 0; t < 4; ++t) {
      int i = i4 * 4 + t;
      D[i] = __fadd_rn(__fmul_rn(yn[i], uav[t]), __fmul_rn(yn[i + 32], ubv[t]));
    }
  }
#pragma unroll
  for (int i = 0; i < 16; ++i) D[i] = __fadd_rn(D[i], D[i + 16]);
#pragma unroll
  for (int i = 0; i < 8; ++i)  D[i] = __fadd_rn(D[i], D[i + 8]);
#pragma unroll
  for (int i = 0; i < 4; ++i)  D[i] = __fadd_rn(D[i], D[i + 4]);
#pragma unroll
  for (int i = 0; i < 2; ++i)  D[i] = __fadd_rn(D[i], D[i + 2]);
  float s = __fadd_rn(D[0], D[1]);
  score1_tail(s, lane, b, item, nb, nrel, out0, ap1_out, s1_idx, s1_rel, s1_ent, lmp1);
}

// ------- step2a (path A): compact Eg rows (L2-resident) + stable top-32 ------
__global__ __launch_bounds__(256) void k_score2e(
    const int* __restrict__ users, const int* __restrict__ s1_rel,
    const float* __restrict__ U, const float* __restrict__ Eg,
    const int* __restrict__ allc, int* __restrict__ kept, int N) {
  int wid = threadIdx.x >> 6, lane = threadIdx.x & 63;
  int n = rfl(blockIdx.x * 4 + wid);
  if (n >= N) return;
  int b = n >> 2;
  int rel = rfl(s1_rel[n]);
  int usr = rfl(users[b]);
  int ent = allc[rel * 64 + lane];
  const float* ur = U + (size_t)usr * 64;
  const float4* e4 = reinterpret_cast<const float4*>(Eg + ((size_t)rel * 64 + lane) * 64);
  float s = 0.f;
#pragma unroll
  for (int j4 = 0; j4 < 16; ++j4) {
    float4 t = e4[j4];
    s = fmaf(ur[4 * j4 + 0], t.x, s);
    s = fmaf(ur[4 * j4 + 1], t.y, s);
    s = fmaf(ur[4 * j4 + 2], t.z, s);
    s = fmaf(ur[4 * j4 + 3], t.w, s);
  }
  int rank = 0;
  for (int k2 = 0; k2 < 64; ++k2) {
    float sv = __shfl(s, k2);
    rank += (sv > s || (sv == s && k2 < lane)) ? 1 : 0;
  }
  if (rank < 32) kept[n * 32 + rank] = (lane << 18) | ent;
}

// ------- step2a (path B fallback): scattered E ------------------------------
__global__ __launch_bounds__(256) void k_score2(
    const int* __restrict__ users, const int* __restrict__ s1_rel,
    const float* __restrict__ U, const float* __restrict__ E,
    const int* __restrict__ allc, int* __restrict__ kept, int N) {
  int wid = threadIdx.x >> 6, lane = threadIdx.x & 63;
  int n = rfl(blockIdx.x * 4 + wid);
  if (n >= N) return;
  int b = n >> 2;
  int rel = rfl(s1_rel[n]);
  int usr = rfl(users[b]);
  int ent = allc[rel * 64 + lane];
  const float* ur = U + (size_t)usr * 64;
  const float4* e4 = reinterpret_cast<const float4*>(E + (size_t)ent * 64);
  float s = 0.f;
#pragma unroll
  for (int j4 = 0; j4 < 16; ++j4) {
    float4 t = e4[j4];
    s = fmaf(ur[4 * j4 + 0], t.x, s);
    s = fmaf(ur[4 * j4 + 1], t.y, s);
    s = fmaf(ur[4 * j4 + 2], t.z, s);
    s = fmaf(ur[4 * j4 + 3], t.w, s);
  }
  int rank = 0;
  for (int k2 = 0; k2 < 64; ++k2) {
    float sv = __shfl(s, k2);
    rank += (sv > s || (sv == s && k2 < lane)) ? 1 : 0;
  }
  if (rank < 32) kept[n * 32 + rank] = (lane << 18) | ent;
}

// ------- step2b shared body: s2, log_softmax, gumbel sample, scatter ---------
__device__ __forceinline__ void sample_body(
    float q, int n, int b, int lane,
    const int* __restrict__ items, const int* __restrict__ s1_idx,
    int rel, const float* __restrict__ T2c, const int* __restrict__ kept,
    float* __restrict__ p2, int* __restrict__ wkg2) {
  int m = lane & 31;
  int pk = kept[n * 32 + m];
  int c = pk >> 18;
  int ent = pk & 0x3FFFF;
  const float4* c4 = reinterpret_cast<const float4*>(T2c + ((size_t)rel * 64 + c) * 64);
  float s = 0.f;
#pragma unroll
  for (int j4 = 0; j4 < 16; ++j4) {
    float4 t = c4[j4];
    s = fmaf(__shfl(q, 4 * j4 + 0), t.x, s);
    s = fmaf(__shfl(q, 4 * j4 + 1), t.y, s);
    s = fmaf(__shfl(q, 4 * j4 + 2), t.z, s);
    s = fmaf(__shfl(q, 4 * j4 + 3), t.w, s);
  }
  float mx = s;
#pragma unroll
  for (int off = 1; off < 32; off <<= 1) mx = fmaxf(mx, __shfl_xor(mx, off));
  float shv = s - mx;
  float se = expf(shv);
  float sum = se;
#pragma unroll
  for (int off = 1; off < 32; off <<= 1) sum += __shfl_xor(sum, off);
  float logp = shv - logf(sum);
  uint32_t h0, h1;
  threefry2x32(0u, 42u, 0u, (uint32_t)(n * 32 + m), h0, h1);
  uint32_t bits = h0 ^ h1;
  float u0 = __uint_as_float((bits >> 9) | 0x3F800000u) - 1.0f;
  float uu = fmaxf(u0, F32_TINY);
  float g = -logf(-logf(uu));
  float z = g + logp;
  float bz = z; int bm = m;
#pragma unroll
  for (int off = 1; off < 32; off <<= 1) {
    float oz = __shfl_xor(bz, off);
    int om = __shfl_xor(bm, off);
    if (oz > bz || (oz == bz && om < bm)) { bz = oz; bm = om; }
  }
  if (lane == bm) {
    p2[n] = expf(logp);
    int col = s1_idx[n];
    int item = items[b];
    atomicMax(&wkg2[(size_t)item * 64 + col], ((b + 1) << 18) | ent);
  }
}

// ---------- step2b (path A): T1-row read, no transform -----------------------
__global__ __launch_bounds__(256) void k_sample2(
    const int* __restrict__ items,
    const int* __restrict__ s1_idx, const int* __restrict__ s1_rel,
    const int* __restrict__ s1_ent, const float* __restrict__ T1,
    const float* __restrict__ T2c, const float* __restrict__ uiE,
    const int* __restrict__ kept,
    float* __restrict__ p2, int* __restrict__ wkg2, int N) {
  int tid = threadIdx.x, wid = tid >> 6, lane = tid & 63;
  int n = rfl(blockIdx.x * 4 + wid);
  if (n >= N) return;
  int b = n >> 2;
  int rel = rfl(s1_rel[n]);
  int repl = rfl(s1_ent[n]);
  float q = uiE[(size_t)b * 64 + lane] * T1[(size_t)repl * 64 + lane];
  sample_body(q, n, b, lane, items, s1_idx, rel, T2c, kept, p2, wkg2);
}

// ---------- step2b (path B fallback): recompute transform --------------------
__global__ __launch_bounds__(256) void k_sample(
    const int* __restrict__ items,
    const int* __restrict__ s1_idx, const int* __restrict__ s1_rel,
    const int* __restrict__ s1_ent,
    const float* __restrict__ E, const float* __restrict__ W1,
    const float* __restrict__ b1, const float* __restrict__ T2c,
    const float* __restrict__ uiE, const int* __restrict__ kept,
    float* __restrict__ p2, int* __restrict__ wkg2, int N) {
  __shared__ float Wl[4096];
  int tid = threadIdx.x;
  for (int i = tid; i < 4096; i += 256) Wl[i] = W1[i];
  __syncthreads();
  int wid = tid >> 6, lane = tid & 63;
  int n = rfl(blockIdx.x * 4 + wid);
  if (n >= N) return;
  int b = n >> 2;
  int rel = rfl(s1_rel[n]);
  int repl = rfl(s1_ent[n]);
  const float* er = E + (size_t)repl * 64;
  float y = 0.f;
#pragma unroll
  for (int k2 = 0; k2 < 64; ++k2) y = fmaf(er[k2], Wl[k2 * 64 + lane], y);
  y += b1[lane];
  float ss = y * y;
#pragma unroll
  for (int off = 32; off; off >>= 1) ss += __shfl_xor(ss, off);
  float yn = y / fmaxf(sqrtf(ss), EPS_NORM);
  float q = uiE[(size_t)b * 64 + lane] * yn;
  sample_body(q, n, b, lane, items, s1_idx, rel, T2c, kept, p2, wkg2);
}

// ---------------- finalize cf_kg2 and ap2 (merged) ---------------------------
__global__ __launch_bounds__(256) void k_fin(const int* __restrict__ wkg2,
                                             const float* __restrict__ p2,
                                             const float* __restrict__ lmp1,
                                             float* __restrict__ out2,
                                             float* __restrict__ out3,
                                             int n, int B) {
  int i = blockIdx.x * 256 + threadIdx.x;
  if (i < n) out2[i] = (float)(wkg2[i] & 0x3FFFF);
  if (i < B) {
    float a = ((p2[i * 4] + p2[i * 4 + 1]) + p2[i * 4 + 2]) + p2[i * 4 + 3];
    out3[i] = lmp1[i] + logf(a * 0.25f);
  }
}

// -----------------------------------------------------------------------------
extern "C" void kernel_launch(void* const* d_in, const int* in_sizes, int n_in,
                              void* d_out, int out_size, void* d_ws, size_t ws_size,
                              hipStream_t stream) {
  const int*   users = (const int*)d_in[0];
  const int*   items = (const int*)d_in[1];
  const int*   kg    = (const int*)d_in[2];
  const int*   allc  = (const int*)d_in[3];
  const int*   nrel  = (const int*)d_in[4];
  const float* U     = (const float*)d_in[5];
  const float* E     = (const float*)d_in[6];
  const float* Iemb  = (const float*)d_in[7];
  const float* uiW   = (const float*)d_in[8];
  const float* uib   = (const float*)d_in[9];
  const float* e1W   = (const float*)d_in[10];
  const float* e1b   = (const float*)d_in[11];
  const float* e2W   = (const float*)d_in[12];
  const float* e2b   = (const float*)d_in[13];

  const int B = 4096, NCELL = 3200000, NCAND = 6400, NR4 = 16384, NENT = 200000;

  float* out0    = (float*)d_out;        // cf_kg1 [3.2M]
  float* out_ap1 = out0 + NCELL;         // ap1    [4096]
  float* out2    = out_ap1 + B;          // cf_kg2 [3.2M]
  float* out_ap2 = out2 + NCELL;         // ap2    [4096]

  float* T2c  = (float*)d_ws;            // 409,600 f
  float* uiE  = T2c + 409600;            // 262,144 f
  int*   wkg2 = (int*)(uiE + 262144);    // 3,200,000 i
  int*   s1i  = wkg2 + NCELL;            // 16384
  int*   s1r  = s1i + NR4;               // 16384
  int*   s1e  = s1r + NR4;               // 16384
  int*   kept = s1e + NR4;               // 524,288
  float* p2   = (float*)(kept + 524288); // 16384
  float* lmp1 = p2 + NR4;                // 4096
  float* T1   = lmp1 + B;                // 12,800,000 f (51.2 MB), path A only
  float* Eg   = out2;                    // raw cand rows, scratch in out2 region
                                         // (k_fin overwrites out2 afterwards)
  const size_t WS_NEED = ((size_t)(T1 + (size_t)NENT * 64) - (size_t)d_ws);
  const bool pathA = ws_size >= WS_NEED;

  if (pathA) {
    // phase1: T1 (782 blks) + T2c/Eg (25) + init (256) + ui (1024) = 2087
    k_phase1<<<2087, 256, 0, stream>>>(E, allc, e1W, e1b, e2W, e2b, U, users,
                                       Iemb, uiW, uib, kg, T1, T2c, Eg, uiE,
                                       out0, wkg2);
    k_score1g<<<B / 4, 256, 0, stream>>>(items, kg, nrel, T1, uiE,
                                         out0, out_ap1, s1i, s1r, s1e, lmp1);
    k_score2e<<<(NR4 + 3) / 4, 256, 0, stream>>>(users, s1r, U, Eg, allc, kept, NR4);
    k_sample2<<<(NR4 + 3) / 4, 256, 0, stream>>>(items, s1i, s1r, s1e, T1, T2c,
                                                 uiE, kept, p2, wkg2, NR4);
  } else {
    k_init<<<(NCELL + 255) / 256, 256, 0, stream>>>(kg, out0, wkg2, NCELL);
    k_ui<<<(B + 3) / 4, 256, 0, stream>>>(U, users, Iemb, uiW, uib, uiE, B);
    k_transform64<<<(NCAND + 3) / 4, 256, 0, stream>>>(E, allc, e2W, e2b, T2c, NCAND);
    k_score1<<<B / 4, 256, 0, stream>>>(items, kg, nrel, E, e1W, e1b, uiE,
                                        out0, out_ap1, s1i, s1r, s1e, lmp1);
    k_score2<<<(NR4 + 3) / 4, 256, 0, stream>>>(users, s1r, U, E, allc, kept, NR4);
    k_sample<<<(NR4 + 3) / 4, 256, 0, stream>>>(items, s1i, s1r, s1e, E, e1W, e1b,
                                                T2c, uiE, kept, p2, wkg2, NR4);
  }
  k_fin<<<(NCELL + 255) / 256, 256, 0, stream>>>(wkg2, p2, lmp1, out2, out_ap2,
                                                 NCELL, B);
}

// Round 6
// 205.567 us; speedup vs baseline: 1.3104x; 1.3104x over previous
//
#include <hip/hip_runtime.h>
#include <stdint.h>

#define EPS_NORM 1e-12f
#define F32_TINY 1.17549435e-38f

static __device__ __forceinline__ int rfl(int v) {
  return __builtin_amdgcn_readfirstlane(v);
}

// ---------------- Threefry2x32 (exact JAX replica, 20 rounds) ----------------
__device__ __forceinline__ void threefry2x32(uint32_t k0, uint32_t k1,
                                             uint32_t x0, uint32_t x1,
                                             uint32_t& o0, uint32_t& o1) {
  uint32_t ks2 = k0 ^ k1 ^ 0x1BD11BDAu;
  x0 += k0; x1 += k1;
#define TF_ROT(r) { x0 += x1; x1 = (x1 << (r)) | (x1 >> (32 - (r))); x1 ^= x0; }
  TF_ROT(13) TF_ROT(15) TF_ROT(26) TF_ROT(6)
  x0 += k1; x1 += ks2 + 1u;
  TF_ROT(17) TF_ROT(29) TF_ROT(16) TF_ROT(24)
  x0 += ks2; x1 += k0 + 2u;
  TF_ROT(13) TF_ROT(15) TF_ROT(26) TF_ROT(6)
  x0 += k0; x1 += k1 + 3u;
  TF_ROT(17) TF_ROT(29) TF_ROT(16) TF_ROT(24)
  x0 += k1; x1 += ks2 + 4u;
  TF_ROT(13) TF_ROT(15) TF_ROT(26) TF_ROT(6)
  x0 += ks2; x1 += k0 + 5u;
#undef TF_ROT
  o0 = x0; o1 = x1;
}

// ===== j-tile matmul step: y[JT*16..+15] += e[k] * W[k][JT*16..+15] ==========
// W from LDS at WAVE-UNIFORM addresses (broadcast, conflict-free).
// E streamed in 8-float chunks (static reg indexing). k ascending (exactness).
template <int JT>
__device__ __forceinline__ void tile_mm(const float4* __restrict__ Er,
                                        const float4* __restrict__ W4,
                                        float (&y)[64]) {
#pragma unroll 1
  for (int kc = 0; kc < 8; ++kc) {
    float4 ea = Er[kc * 2], eb = Er[kc * 2 + 1];
    float ev[8] = {ea.x, ea.y, ea.z, ea.w, eb.x, eb.y, eb.z, eb.w};
#pragma unroll
    for (int ki = 0; ki < 8; ++ki) {
      int k = kc * 8 + ki;
      float4 w0 = W4[k * 16 + JT * 4 + 0];   // uniform ds_read_b128
      float4 w1 = W4[k * 16 + JT * 4 + 1];
      float4 w2 = W4[k * 16 + JT * 4 + 2];
      float4 w3 = W4[k * 16 + JT * 4 + 3];
      float wv[16] = {w0.x, w0.y, w0.z, w0.w, w1.x, w1.y, w1.z, w1.w,
                      w2.x, w2.y, w2.z, w2.w, w3.x, w3.y, w3.z, w3.w};
      float ek = ev[ki];
#pragma unroll
      for (int t = 0; t < 16; ++t)
        y[JT * 16 + t] = fmaf(ek, wv[t], y[JT * 16 + t]);
    }
  }
}

// ========== PHASE 1: T1 (all entities) + T2c/Eg (candidates) + init =========
// blocks [0,782): T1 rows, [782,807): T2c rows + Eg raw copy, [807,1000): init.
// lane = row; W staged once per block in LDS; zero scalar-loads in hot loop.
__global__ __launch_bounds__(256, 4) void k_phase1(
    const float* __restrict__ E, const int* __restrict__ allc,
    const float* __restrict__ W1, const float* __restrict__ b1,
    const float* __restrict__ W2, const float* __restrict__ b2,
    const int* __restrict__ kg,
    float* __restrict__ T1, float* __restrict__ T2c, float* __restrict__ Eg,
    float* __restrict__ out0, int* __restrict__ wkg2) {
  __shared__ float Wl[4160];
  const int blk = blockIdx.x, tid = threadIdx.x;
  const int wv = tid >> 6, lane = tid & 63;
  if (blk < 807) {  // -------- transform roles --------
    const bool isT1 = blk < 782;
    {
      const float* W = isT1 ? W1 : W2;
      const float* bias = isT1 ? b1 : b2;
      for (int i = tid; i < 4096; i += 256) Wl[i] = W[i];
      if (tid < 64) Wl[4096 + tid] = bias[tid];
    }
    __syncthreads();
    int wloc = isT1 ? blk * 4 + wv : (blk - 782) * 4 + wv;
    if (isT1 && wloc >= 3125) return;
    int drow = wloc * 64 + lane;
    int srow = isT1 ? drow : allc[drow];
    const float4* Er = reinterpret_cast<const float4*>(E + (size_t)srow * 64);
    const float4* W4 = reinterpret_cast<const float4*>(Wl);
    float y[64];
#pragma unroll
    for (int j = 0; j < 64; ++j) y[j] = 0.f;
    tile_mm<0>(Er, W4, y);
    tile_mm<1>(Er, W4, y);
    tile_mm<2>(Er, W4, y);
    tile_mm<3>(Er, W4, y);
    // + bias (uniform LDS)
    const float4* B4 = W4 + 1024;
#pragma unroll
    for (int j4 = 0; j4 < 16; ++j4) {
      float4 bb = B4[j4];
      float bv[4] = {bb.x, bb.y, bb.z, bb.w};
#pragma unroll
      for (int t = 0; t < 4; ++t)
        y[j4 * 4 + t] = __fadd_rn(y[j4 * 4 + t], bv[t]);
    }
    // ss butterfly-replica tree (xor 32,16,8,4,2,1)
    float S1[32];
#pragma unroll
    for (int i = 0; i < 32; ++i)
      S1[i] = __fadd_rn(__fmul_rn(y[i], y[i]), __fmul_rn(y[i + 32], y[i + 32]));
#pragma unroll
    for (int i = 0; i < 16; ++i) S1[i] = __fadd_rn(S1[i], S1[i + 16]);
#pragma unroll
    for (int i = 0; i < 8; ++i)  S1[i] = __fadd_rn(S1[i], S1[i + 8]);
#pragma unroll
    for (int i = 0; i < 4; ++i)  S1[i] = __fadd_rn(S1[i], S1[i + 4]);
#pragma unroll
    for (int i = 0; i < 2; ++i)  S1[i] = __fadd_rn(S1[i], S1[i + 2]);
    float ss = __fadd_rn(S1[0], S1[1]);
    float denom = fmaxf(sqrtf(ss), EPS_NORM);
    float* dst = isT1 ? T1 : T2c;
    float4* D4 = reinterpret_cast<float4*>(dst + (size_t)drow * 64);
#pragma unroll
    for (int j4 = 0; j4 < 16; ++j4)
      D4[j4] = make_float4(y[4 * j4] / denom, y[4 * j4 + 1] / denom,
                           y[4 * j4 + 2] / denom, y[4 * j4 + 3] / denom);
    if (!isT1) {  // raw candidate-row copy for k_score2e (L2-hot re-read)
      float4* G4 = reinterpret_cast<float4*>(Eg + (size_t)drow * 64);
#pragma unroll
      for (int t = 0; t < 16; ++t) G4[t] = Er[t];
    }
  } else {  // -------- init role: kg -> out0(float) + wkg2(int) --------
    const int4* kg4 = reinterpret_cast<const int4*>(kg);
    float4* o4 = reinterpret_cast<float4*>(out0);
    int4* w4 = reinterpret_cast<int4*>(wkg2);
    for (int i = (blk - 807) * 256 + tid; i < 800000; i += 193 * 256) {
      int4 v = kg4[i];
      o4[i] = make_float4((float)v.x, (float)v.y, (float)v.z, (float)v.w);
      w4[i] = v;
    }
  }
}

// ================= fallback-path kernels (unchanged from R4) =================
__global__ __launch_bounds__(256) void k_init(const int* __restrict__ kg,
                                              float* __restrict__ out0,
                                              int* __restrict__ wkg2, int n) {
  int i = blockIdx.x * 256 + threadIdx.x;
  if (i < n) { int v = kg[i]; out0[i] = (float)v; wkg2[i] = v; }
}

__device__ __forceinline__ void transform_row(const float4* __restrict__ Er,
                                              const float* __restrict__ W,
                                              const float* __restrict__ bias,
                                              float (&yn)[64]) {
  float y[64];
#pragma unroll
  for (int j = 0; j < 64; ++j) y[j] = 0.f;
  float4 c0 = Er[0], c1 = Er[1], c2 = Er[2], c3 = Er[3];
#pragma unroll 1
  for (int cc = 0; cc < 4; ++cc) {
    float4 n0, n1, n2, n3;
    if (cc < 3) { n0 = Er[cc * 4 + 4]; n1 = Er[cc * 4 + 5];
                  n2 = Er[cc * 4 + 6]; n3 = Er[cc * 4 + 7]; }
    float ev[16] = {c0.x, c0.y, c0.z, c0.w, c1.x, c1.y, c1.z, c1.w,
                    c2.x, c2.y, c2.z, c2.w, c3.x, c3.y, c3.z, c3.w};
#pragma unroll
    for (int k2i = 0; k2i < 16; ++k2i) {
      const float4* Wr = reinterpret_cast<const float4*>(
          W + ((size_t)(cc * 16 + k2i)) * 64);
      float ek = ev[k2i];
#pragma unroll
      for (int j4 = 0; j4 < 16; ++j4) {
        float4 w = Wr[j4];
        y[j4 * 4 + 0] = fmaf(ek, w.x, y[j4 * 4 + 0]);
        y[j4 * 4 + 1] = fmaf(ek, w.y, y[j4 * 4 + 1]);
        y[j4 * 4 + 2] = fmaf(ek, w.z, y[j4 * 4 + 2]);
        y[j4 * 4 + 3] = fmaf(ek, w.w, y[j4 * 4 + 3]);
      }
    }
    c0 = n0; c1 = n1; c2 = n2; c3 = n3;
  }
  const float4* B4 = reinterpret_cast<const float4*>(bias);
#pragma unroll
  for (int j4 = 0; j4 < 16; ++j4) {
    float4 bb = B4[j4];
    float bv[4] = {bb.x, bb.y, bb.z, bb.w};
#pragma unroll
    for (int t = 0; t < 4; ++t) y[j4 * 4 + t] = __fadd_rn(y[j4 * 4 + t], bv[t]);
  }
  float S1[32];
#pragma unroll
  for (int i = 0; i < 32; ++i)
    S1[i] = __fadd_rn(__fmul_rn(y[i], y[i]), __fmul_rn(y[i + 32], y[i + 32]));
#pragma unroll
  for (int i = 0; i < 16; ++i) S1[i] = __fadd_rn(S1[i], S1[i + 16]);
#pragma unroll
  for (int i = 0; i < 8; ++i)  S1[i] = __fadd_rn(S1[i], S1[i + 8]);
#pragma unroll
  for (int i = 0; i < 4; ++i)  S1[i] = __fadd_rn(S1[i], S1[i + 4]);
#pragma unroll
  for (int i = 0; i < 2; ++i)  S1[i] = __fadd_rn(S1[i], S1[i + 2]);
  float ss = __fadd_rn(S1[0], S1[1]);
  float denom = fmaxf(sqrtf(ss), EPS_NORM);
#pragma unroll
  for (int j = 0; j < 64; ++j) yn[j] = y[j] / denom;
}

__global__ __launch_bounds__(256) void k_transform64(
    const float* __restrict__ src, const int* __restrict__ gidx,
    const float* __restrict__ W, const float* __restrict__ bias,
    float* __restrict__ out, int nrows) {
  __shared__ float Wl[4096];
  for (int i = threadIdx.x; i < 4096; i += 256) Wl[i] = W[i];
  __syncthreads();
  int wid = threadIdx.x >> 6, lane = threadIdx.x & 63;
  int row = rfl(blockIdx.x * 4 + wid);
  if (row >= nrows) return;
  int srow = rfl(gidx ? gidx[row] : row);
  const float* er = src + (size_t)srow * 64;
  float y = 0.f;
#pragma unroll
  for (int k = 0; k < 64; ++k) y = fmaf(er[k], Wl[k * 64 + lane], y);
  y += bias[lane];
  float ss = y * y;
#pragma unroll
  for (int off = 32; off; off >>= 1) ss += __shfl_xor(ss, off);
  float yn = y / fmaxf(sqrtf(ss), EPS_NORM);
  out[(size_t)row * 64 + lane] = yn;
}

__global__ __launch_bounds__(256) void k_ui(
    const float* __restrict__ U, const int* __restrict__ users,
    const float* __restrict__ Iemb, const float* __restrict__ W,
    const float* __restrict__ bias, float* __restrict__ out, int B) {
  __shared__ float Wl[8192];
  for (int i = threadIdx.x; i < 8192; i += 256) Wl[i] = W[i];
  __syncthreads();
  int wid = threadIdx.x >> 6, lane = threadIdx.x & 63;
  int b = rfl(blockIdx.x * 4 + wid);
  if (b >= B) return;
  int usr = rfl(users[b]);
  const float* ur = U + (size_t)usr * 64;
  const float* ir = Iemb + (size_t)b * 64;
  float y = 0.f;
#pragma unroll
  for (int k = 0; k < 64; ++k) y = fmaf(ur[k], Wl[k * 64 + lane], y);
#pragma unroll
  for (int k = 0; k < 64; ++k) y = fmaf(ir[k], Wl[(64 + k) * 64 + lane], y);
  y += bias[lane];
  float ss = y * y;
#pragma unroll
  for (int off = 32; off; off >>= 1) ss += __shfl_xor(ss, off);
  float yn = y / fmaxf(sqrtf(ss), EPS_NORM);
  out[(size_t)b * 64 + lane] = yn;
}

// ------------------ step1 tail (softmax + top4), shared ----------------------
__device__ __forceinline__ void score1_tail(
    float s, int lane, int b, int item, int nb,
    const int* __restrict__ nrel,
    float* __restrict__ out0, float* __restrict__ ap1_out,
    int* __restrict__ s1_idx, int* __restrict__ s1_rel, int* __restrict__ s1_ent,
    float* __restrict__ lmp1) {
  float m = s;
#pragma unroll
  for (int off = 32; off; off >>= 1) m = fmaxf(m, __shfl_xor(m, off));
  float ex = expf(s - m);
  float sum = ex;
#pragma unroll
  for (int off = 32; off; off >>= 1) sum += __shfl_xor(sum, off);
  float p = ex / sum;
  int rank = 0;
  for (int k2 = 0; k2 < 64; ++k2) {
    float pv = __shfl(p, k2);
    rank += (pv > p || (pv == p && k2 < lane)) ? 1 : 0;
  }
  float acc = 0.f;
#pragma unroll
  for (int rr = 0; rr < 4; ++rr) {
    unsigned long long msk = __ballot(rank == rr);
    int src = __ffsll(msk) - 1;
    acc += __shfl(p, src);
  }
  float lm = logf(acc * 0.25f);
  if (lane == 0) { ap1_out[b] = lm; lmp1[b] = lm; }
  if (rank < 4) {
    s1_idx[b * 4 + rank] = lane;
    s1_ent[b * 4 + rank] = nb;
    s1_rel[b * 4 + rank] = nrel[(size_t)item * 64 + lane];
    out0[(size_t)item * 64 + lane] = 0.0f;
  }
}

// ---------- step1 (path A): gather T1 rows + in-register dot + tail ----------
__global__ __launch_bounds__(256) void k_score1g(
    const int* __restrict__ items, const int* __restrict__ kg,
    const int* __restrict__ nrel, const float* __restrict__ T1,
    const float* __restrict__ uiE,
    float* __restrict__ out0, float* __restrict__ ap1_out,
    int* __restrict__ s1_idx, int* __restrict__ s1_rel, int* __restrict__ s1_ent,
    float* __restrict__ lmp1) {
  int tid = threadIdx.x, wv = tid >> 6, lane = tid & 63;
  int b = rfl(blockIdx.x * 4 + wv);
  int item = rfl(items[b]);
  int nb = kg[(size_t)item * 64 + lane];
  const float4* R = reinterpret_cast<const float4*>(T1 + (size_t)nb * 64);
  float yn[64];
#pragma unroll
  for (int j4 = 0; j4 < 16; ++j4) {
    float4 v = R[j4];
    yn[4 * j4] = v.x; yn[4 * j4 + 1] = v.y; yn[4 * j4 + 2] = v.z; yn[4 * j4 + 3] = v.w;
  }
  const float4* Ur = reinterpret_cast<const float4*>(uiE + (size_t)b * 64);
  float D[32];
#pragma unroll
  for (int i4 = 0; i4 < 8; ++i4) {
    float4 ua = Ur[i4], ub = Ur[i4 + 8];
    float uav[4] = {ua.x, ua.y, ua.z, ua.w};
    float ubv[4] = {ub.x, ub.y, ub.z, ub.w};
#pragma unroll
    for (int t = 0; t < 4; ++t) {
      int i = i4 * 4 + t;
      D[i] = __fadd_rn(__fmul_rn(yn[i], uav[t]), __fmul_rn(yn[i + 32], ubv[t]));
    }
  }
#pragma unroll
  for (int i = 0; i < 16; ++i) D[i] = __fadd_rn(D[i], D[i + 16]);
#pragma unroll
  for (int i = 0; i < 8; ++i)  D[i] = __fadd_rn(D[i], D[i + 8]);
#pragma unroll
  for (int i = 0; i < 4; ++i)  D[i] = __fadd_rn(D[i], D[i + 4]);
#pragma unroll
  for (int i = 0; i < 2; ++i)  D[i] = __fadd_rn(D[i], D[i + 2]);
  float s = __fadd_rn(D[0], D[1]);
  score1_tail(s, lane, b, item, nb, nrel, out0, ap1_out, s1_idx, s1_rel, s1_ent, lmp1);
}

// ---------- step1 (path B fallback): fused transform + dot + tail ------------
__global__ __launch_bounds__(256) void k_score1(
    const int* __restrict__ items, const int* __restrict__ kg,
    const int* __restrict__ nrel, const float* __restrict__ E,
    const float* __restrict__ W1, const float* __restrict__ b1,
    const float* __restrict__ uiE,
    float* __restrict__ out0, float* __restrict__ ap1_out,
    int* __restrict__ s1_idx, int* __restrict__ s1_rel, int* __restrict__ s1_ent,
    float* __restrict__ lmp1) {
  int tid = threadIdx.x, wv = tid >> 6, lane = tid & 63;
  int b = rfl(blockIdx.x * 4 + wv);
  int item = rfl(items[b]);
  int nb = kg[(size_t)item * 64 + lane];
  const float4* Er = reinterpret_cast<const float4*>(E + (size_t)nb * 64);
  float yn[64];
  transform_row(Er, W1, b1, yn);
  const float4* Ur = reinterpret_cast<const float4*>(uiE + (size_t)b * 64);
  float D[32];
#pragma unroll
  for (int i4 = 0; i4 < 8; ++i4) {
    float4 ua = Ur[i4], ub = Ur[i4 + 8];
    float uav[4] = {ua.x, ua.y, ua.z, ua.w};
    float ubv[4] = {ub.x, ub.y, ub.z, ub.w};
#pragma unroll
    for (int t = 0; t < 4; ++t) {
      int i = i4 * 4 + t;
      D[i] = __fadd_rn(__fmul_rn(yn[i], uav[t]), __fmul_rn(yn[i + 32], ubv[t]));
    }
  }
#pragma unroll
  for (int i = 0; i < 16; ++i) D[i] = __fadd_rn(D[i], D[i + 16]);
#pragma unroll
  for (int i = 0; i < 8; ++i)  D[i] = __fadd_rn(D[i], D[i + 8]);
#pragma unroll
  for (int i = 0; i < 4; ++i)  D[i] = __fadd_rn(D[i], D[i + 4]);
#pragma unroll
  for (int i = 0; i < 2; ++i)  D[i] = __fadd_rn(D[i], D[i + 2]);
  float s = __fadd_rn(D[0], D[1]);
  score1_tail(s, lane, b, item, nb, nrel, out0, ap1_out, s1_idx, s1_rel, s1_ent, lmp1);
}

// ------- step2a (path A): compact Eg rows (L2-resident) + stable top-32 ------
__global__ __launch_bounds__(256) void k_score2e(
    const int* __restrict__ users, const int* __restrict__ s1_rel,
    const float* __restrict__ U, const float* __restrict__ Eg,
    const int* __restrict__ allc, int* __restrict__ kept, int N) {
  int wid = threadIdx.x >> 6, lane = threadIdx.x & 63;
  int n = rfl(blockIdx.x * 4 + wid);
  if (n >= N) return;
  int b = n >> 2;
  int rel = rfl(s1_rel[n]);
  int usr = rfl(users[b]);
  int ent = allc[rel * 64 + lane];
  const float* ur = U + (size_t)usr * 64;
  const float4* e4 = reinterpret_cast<const float4*>(Eg + ((size_t)rel * 64 + lane) * 64);
  float s = 0.f;
#pragma unroll
  for (int j4 = 0; j4 < 16; ++j4) {
    float4 t = e4[j4];
    s = fmaf(ur[4 * j4 + 0], t.x, s);
    s = fmaf(ur[4 * j4 + 1], t.y, s);
    s = fmaf(ur[4 * j4 + 2], t.z, s);
    s = fmaf(ur[4 * j4 + 3], t.w, s);
  }
  int rank = 0;
  for (int k2 = 0; k2 < 64; ++k2) {
    float sv = __shfl(s, k2);
    rank += (sv > s || (sv == s && k2 < lane)) ? 1 : 0;
  }
  if (rank < 32) kept[n * 32 + rank] = (lane << 18) | ent;
}

// ------- step2a (path B fallback): scattered E ------------------------------
__global__ __launch_bounds__(256) void k_score2(
    const int* __restrict__ users, const int* __restrict__ s1_rel,
    const float* __restrict__ U, const float* __restrict__ E,
    const int* __restrict__ allc, int* __restrict__ kept, int N) {
  int wid = threadIdx.x >> 6, lane = threadIdx.x & 63;
  int n = rfl(blockIdx.x * 4 + wid);
  if (n >= N) return;
  int b = n >> 2;
  int rel = rfl(s1_rel[n]);
  int usr = rfl(users[b]);
  int ent = allc[rel * 64 + lane];
  const float* ur = U + (size_t)usr * 64;
  const float4* e4 = reinterpret_cast<const float4*>(E + (size_t)ent * 64);
  float s = 0.f;
#pragma unroll
  for (int j4 = 0; j4 < 16; ++j4) {
    float4 t = e4[j4];
    s = fmaf(ur[4 * j4 + 0], t.x, s);
    s = fmaf(ur[4 * j4 + 1], t.y, s);
    s = fmaf(ur[4 * j4 + 2], t.z, s);
    s = fmaf(ur[4 * j4 + 3], t.w, s);
  }
  int rank = 0;
  for (int k2 = 0; k2 < 64; ++k2) {
    float sv = __shfl(s, k2);
    rank += (sv > s || (sv == s && k2 < lane)) ? 1 : 0;
  }
  if (rank < 32) kept[n * 32 + rank] = (lane << 18) | ent;
}

// ------- step2b shared body: s2, log_softmax, gumbel sample, scatter ---------
__device__ __forceinline__ void sample_body(
    float q, int n, int b, int lane,
    const int* __restrict__ items, const int* __restrict__ s1_idx,
    int rel, const float* __restrict__ T2c, const int* __restrict__ kept,
    float* __restrict__ p2, int* __restrict__ wkg2) {
  int m = lane & 31;
  int pk = kept[n * 32 + m];
  int c = pk >> 18;
  int ent = pk & 0x3FFFF;
  const float4* c4 = reinterpret_cast<const float4*>(T2c + ((size_t)rel * 64 + c) * 64);
  float s = 0.f;
#pragma unroll
  for (int j4 = 0; j4 < 16; ++j4) {
    float4 t = c4[j4];
    s = fmaf(__shfl(q, 4 * j4 + 0), t.x, s);
    s = fmaf(__shfl(q, 4 * j4 + 1), t.y, s);
    s = fmaf(__shfl(q, 4 * j4 + 2), t.z, s);
    s = fmaf(__shfl(q, 4 * j4 + 3), t.w, s);
  }
  float mx = s;
#pragma unroll
  for (int off = 1; off < 32; off <<= 1) mx = fmaxf(mx, __shfl_xor(mx, off));
  float shv = s - mx;
  float se = expf(shv);
  float sum = se;
#pragma unroll
  for (int off = 1; off < 32; off <<= 1) sum += __shfl_xor(sum, off);
  float logp = shv - logf(sum);
  uint32_t h0, h1;
  threefry2x32(0u, 42u, 0u, (uint32_t)(n * 32 + m), h0, h1);
  uint32_t bits = h0 ^ h1;
  float u0 = __uint_as_float((bits >> 9) | 0x3F800000u) - 1.0f;
  float uu = fmaxf(u0, F32_TINY);
  float g = -logf(-logf(uu));
  float z = g + logp;
  float bz = z; int bm = m;
#pragma unroll
  for (int off = 1; off < 32; off <<= 1) {
    float oz = __shfl_xor(bz, off);
    int om = __shfl_xor(bm, off);
    if (oz > bz || (oz == bz && om < bm)) { bz = oz; bm = om; }
  }
  if (lane == bm) {
    p2[n] = expf(logp);
    int col = s1_idx[n];
    int item = items[b];
    atomicMax(&wkg2[(size_t)item * 64 + col], ((b + 1) << 18) | ent);
  }
}

// ---------- step2b (path A): T1-row read, no transform -----------------------
__global__ __launch_bounds__(256) void k_sample2(
    const int* __restrict__ items,
    const int* __restrict__ s1_idx, const int* __restrict__ s1_rel,
    const int* __restrict__ s1_ent, const float* __restrict__ T1,
    const float* __restrict__ T2c, const float* __restrict__ uiE,
    const int* __restrict__ kept,
    float* __restrict__ p2, int* __restrict__ wkg2, int N) {
  int tid = threadIdx.x, wid = tid >> 6, lane = tid & 63;
  int n = rfl(blockIdx.x * 4 + wid);
  if (n >= N) return;
  int b = n >> 2;
  int rel = rfl(s1_rel[n]);
  int repl = rfl(s1_ent[n]);
  float q = uiE[(size_t)b * 64 + lane] * T1[(size_t)repl * 64 + lane];
  sample_body(q, n, b, lane, items, s1_idx, rel, T2c, kept, p2, wkg2);
}

// ---------- step2b (path B fallback): recompute transform --------------------
__global__ __launch_bounds__(256) void k_sample(
    const int* __restrict__ items,
    const int* __restrict__ s1_idx, const int* __restrict__ s1_rel,
    const int* __restrict__ s1_ent,
    const float* __restrict__ E, const float* __restrict__ W1,
    const float* __restrict__ b1, const float* __restrict__ T2c,
    const float* __restrict__ uiE, const int* __restrict__ kept,
    float* __restrict__ p2, int* __restrict__ wkg2, int N) {
  __shared__ float Wl[4096];
  int tid = threadIdx.x;
  for (int i = tid; i < 4096; i += 256) Wl[i] = W1[i];
  __syncthreads();
  int wid = tid >> 6, lane = tid & 63;
  int n = rfl(blockIdx.x * 4 + wid);
  if (n >= N) return;
  int b = n >> 2;
  int rel = rfl(s1_rel[n]);
  int repl = rfl(s1_ent[n]);
  const float* er = E + (size_t)repl * 64;
  float y = 0.f;
#pragma unroll
  for (int k2 = 0; k2 < 64; ++k2) y = fmaf(er[k2], Wl[k2 * 64 + lane], y);
  y += b1[lane];
  float ss = y * y;
#pragma unroll
  for (int off = 32; off; off >>= 1) ss += __shfl_xor(ss, off);
  float yn = y / fmaxf(sqrtf(ss), EPS_NORM);
  float q = uiE[(size_t)b * 64 + lane] * yn;
  sample_body(q, n, b, lane, items, s1_idx, rel, T2c, kept, p2, wkg2);
}

// ---------------- finalize cf_kg2 and ap2 (merged) ---------------------------
__global__ __launch_bounds__(256) void k_fin(const int* __restrict__ wkg2,
                                             const float* __restrict__ p2,
                                             const float* __restrict__ lmp1,
                                             float* __restrict__ out2,
                                             float* __restrict__ out3,
                                             int n, int B) {
  int i = blockIdx.x * 256 + threadIdx.x;
  if (i < n) out2[i] = (float)(wkg2[i] & 0x3FFFF);
  if (i < B) {
    float a = ((p2[i * 4] + p2[i * 4 + 1]) + p2[i * 4 + 2]) + p2[i * 4 + 3];
    out3[i] = lmp1[i] + logf(a * 0.25f);
  }
}

// -----------------------------------------------------------------------------
extern "C" void kernel_launch(void* const* d_in, const int* in_sizes, int n_in,
                              void* d_out, int out_size, void* d_ws, size_t ws_size,
                              hipStream_t stream) {
  const int*   users = (const int*)d_in[0];
  const int*   items = (const int*)d_in[1];
  const int*   kg    = (const int*)d_in[2];
  const int*   allc  = (const int*)d_in[3];
  const int*   nrel  = (const int*)d_in[4];
  const float* U     = (const float*)d_in[5];
  const float* E     = (const float*)d_in[6];
  const float* Iemb  = (const float*)d_in[7];
  const float* uiW   = (const float*)d_in[8];
  const float* uib   = (const float*)d_in[9];
  const float* e1W   = (const float*)d_in[10];
  const float* e1b   = (const float*)d_in[11];
  const float* e2W   = (const float*)d_in[12];
  const float* e2b   = (const float*)d_in[13];

  const int B = 4096, NCELL = 3200000, NCAND = 6400, NR4 = 16384, NENT = 200000;

  float* out0    = (float*)d_out;        // cf_kg1 [3.2M]
  float* out_ap1 = out0 + NCELL;         // ap1    [4096]
  float* out2    = out_ap1 + B;          // cf_kg2 [3.2M]
  float* out_ap2 = out2 + NCELL;         // ap2    [4096]

  float* T2c  = (float*)d_ws;            // 409,600 f
  float* uiE  = T2c + 409600;            // 262,144 f
  int*   wkg2 = (int*)(uiE + 262144);    // 3,200,000 i
  int*   s1i  = wkg2 + NCELL;            // 16384
  int*   s1r  = s1i + NR4;               // 16384
  int*   s1e  = s1r + NR4;               // 16384
  int*   kept = s1e + NR4;               // 524,288
  float* p2   = (float*)(kept + 524288); // 16384
  float* lmp1 = p2 + NR4;                // 4096
  float* T1   = lmp1 + B;                // 12,800,000 f (51.2 MB), path A only
  float* Eg   = out2;                    // raw cand rows, scratch in out2 region
                                         // (k_fin overwrites out2 afterwards)
  const size_t WS_NEED = ((size_t)(T1 + (size_t)NENT * 64) - (size_t)d_ws);
  const bool pathA = ws_size >= WS_NEED;

  if (pathA) {
    // phase1: T1 (782 blks) + T2c/Eg (25) + init (193) = 1000 blocks
    k_phase1<<<1000, 256, 0, stream>>>(E, allc, e1W, e1b, e2W, e2b, kg,
                                       T1, T2c, Eg, out0, wkg2);
    k_ui<<<(B + 3) / 4, 256, 0, stream>>>(U, users, Iemb, uiW, uib, uiE, B);
    k_score1g<<<B / 4, 256, 0, stream>>>(items, kg, nrel, T1, uiE,
                                         out0, out_ap1, s1i, s1r, s1e, lmp1);
    k_score2e<<<(NR4 + 3) / 4, 256, 0, stream>>>(users, s1r, U, Eg, allc, kept, NR4);
    k_sample2<<<(NR4 + 3) / 4, 256, 0, stream>>>(items, s1i, s1r, s1e, T1, T2c,
                                                 uiE, kept, p2, wkg2, NR4);
  } else {
    k_init<<<(NCELL + 255) / 256, 256, 0, stream>>>(kg, out0, wkg2, NCELL);
    k_ui<<<(B + 3) / 4, 256, 0, stream>>>(U, users, Iemb, uiW, uib, uiE, B);
    k_transform64<<<(NCAND + 3) / 4, 256, 0, stream>>>(E, allc, e2W, e2b, T2c, NCAND);
    k_score1<<<B / 4, 256, 0, stream>>>(items, kg, nrel, E, e1W, e1b, uiE,
                                        out0, out_ap1, s1i, s1r, s1e, lmp1);
    k_score2<<<(NR4 + 3) / 4, 256, 0, stream>>>(users, s1r, U, E, allc, kept, NR4);
    k_sample<<<(NR4 + 3) / 4, 256, 0, stream>>>(items, s1i, s1r, s1e, E, e1W, e1b,
                                                T2c, uiE, kept, p2, wkg2, NR4);
  }
  k_fin<<<(NCELL + 255) / 256, 256, 0, stream>>>(wkg2, p2, lmp1, out2, out_ap2,
                                                 NCELL, B);
}

// Round 7
// 138.359 us; speedup vs baseline: 1.9469x; 1.4858x over previous
//
#include <hip/hip_runtime.h>
#include <stdint.h>

#define EPS_NORM 1e-12f
#define F32_TINY 1.17549435e-38f

static __device__ __forceinline__ int rfl(int v) {
  return __builtin_amdgcn_readfirstlane(v);
}

// ---------------- Threefry2x32 (exact JAX replica, 20 rounds) ----------------
__device__ __forceinline__ void threefry2x32(uint32_t k0, uint32_t k1,
                                             uint32_t x0, uint32_t x1,
                                             uint32_t& o0, uint32_t& o1) {
  uint32_t ks2 = k0 ^ k1 ^ 0x1BD11BDAu;
  x0 += k0; x1 += k1;
#define TF_ROT(r) { x0 += x1; x1 = (x1 << (r)) | (x1 >> (32 - (r))); x1 ^= x0; }
  TF_ROT(13) TF_ROT(15) TF_ROT(26) TF_ROT(6)
  x0 += k1; x1 += ks2 + 1u;
  TF_ROT(17) TF_ROT(29) TF_ROT(16) TF_ROT(24)
  x0 += ks2; x1 += k0 + 2u;
  TF_ROT(13) TF_ROT(15) TF_ROT(26) TF_ROT(6)
  x0 += k0; x1 += k1 + 3u;
  TF_ROT(17) TF_ROT(29) TF_ROT(16) TF_ROT(24)
  x0 += k1; x1 += ks2 + 4u;
  TF_ROT(13) TF_ROT(15) TF_ROT(26) TF_ROT(6)
  x0 += ks2; x1 += k0 + 5u;
#undef TF_ROT
  o0 = x0; o1 = x1;
}

// ========== PHASE 1: T1 (all entities) + T2c/Eg (candidates) + init =========
// Transform blocks: wave = 32 rows x 64 cols GEMM tile.
//   lane (rg=lane>>3, cg=lane&7) owns rows {rg*4+ri}, cols {ci*8+cg}.
//   Per k: 1 ds_read_b128 eT (4 rows, 8-lane broadcast, conflict-free)
//        + 2 ds_read_b128 swizzled-W (8 cols, 2-way = free) -> 32 fma.
//   ss reduction = in-lane ci-pair stages (^32,^16,^8) + shfl_xor 4,2,1:
//   exact butterfly-replica (IEEE add commutativity) -> bitwise identical.
__global__ __launch_bounds__(256, 3) void k_phase1(
    const float* __restrict__ E, const int* __restrict__ allc,
    const float* __restrict__ W1, const float* __restrict__ b1,
    const float* __restrict__ W2, const float* __restrict__ b2,
    const int* __restrict__ kg,
    float* __restrict__ T1, float* __restrict__ T2c, float* __restrict__ Eg,
    float* __restrict__ out0, int* __restrict__ wkg2) {
  __shared__ float Wl[4096];      // swizzled: Wl[k*64 + (c&7)*8 + (c>>3)]
  __shared__ float eT[4][2048];   // per-wave transposed 32-row tile [k][r]
  const int blk = blockIdx.x, tid = threadIdx.x;
  const int wv = tid >> 6, lane = tid & 63;
  const int NT1B = 1563, NT2B = 50;   // 1563*128 >= 200000; 50*128 = 6400
  if (blk < NT1B + NT2B) {
    const bool isT1 = blk < NT1B;
    {  // stage swizzled W
      const float* W = isT1 ? W1 : W2;
      for (int idx = tid; idx < 4096; idx += 256) {
        int k = idx >> 6, c = idx & 63;
        Wl[k * 64 + ((c & 7) * 8 + (c >> 3))] = W[idx];
      }
    }
    int rbase = (isT1 ? blk * 4 + wv : (blk - NT1B) * 4 + wv) * 32;
    bool active = !isT1 || rbase < 200000;
    int half = lane >> 5, r = lane & 31;
    if (active) {  // stage 32 rows transposed (lane = (half, r))
      int srow = isT1 ? (rbase + r) : allc[rbase + r];
      const float4* Er =
          reinterpret_cast<const float4*>(E + (size_t)srow * 64 + half * 32);
      float4 c0 = Er[0], c1 = Er[1], c2 = Er[2], c3 = Er[3];
      float4 c4 = Er[4], c5 = Er[5], c6 = Er[6], c7 = Er[7];
      float ev[32] = {c0.x, c0.y, c0.z, c0.w, c1.x, c1.y, c1.z, c1.w,
                      c2.x, c2.y, c2.z, c2.w, c3.x, c3.y, c3.z, c3.w,
                      c4.x, c4.y, c4.z, c4.w, c5.x, c5.y, c5.z, c5.w,
                      c6.x, c6.y, c6.z, c6.w, c7.x, c7.y, c7.z, c7.w};
      float* et = eT[wv];
#pragma unroll
      for (int kk = 0; kk < 32; ++kk)
        et[(half * 32 + kk) * 32 + r] = ev[kk];   // stride-1 across lanes: free
      if (!isT1) {  // raw candidate-row copy for k_score2e
        float4* G =
            reinterpret_cast<float4*>(Eg + (size_t)(rbase + r) * 64 + half * 32);
        G[0] = c0; G[1] = c1; G[2] = c2; G[3] = c3;
        G[4] = c4; G[5] = c5; G[6] = c6; G[7] = c7;
      }
    }
    __syncthreads();
    if (!active) return;
    const int rg = lane >> 3, cg = lane & 7;
    float y[4][8];
#pragma unroll
    for (int ri = 0; ri < 4; ++ri)
#pragma unroll
      for (int ci = 0; ci < 8; ++ci) y[ri][ci] = 0.f;
    const float4* eT4 = reinterpret_cast<const float4*>(eT[wv]);
    const float4* W4 = reinterpret_cast<const float4*>(Wl);
#pragma unroll 8
    for (int k = 0; k < 64; ++k) {
      float4 e4 = eT4[k * 8 + rg];            // rows rg*4..+3, broadcast x8
      float4 wa = W4[k * 16 + cg * 2];        // cols {cg, 8+cg, 16+cg, 24+cg}
      float4 wb = W4[k * 16 + cg * 2 + 1];    // cols {32+cg, ..., 56+cg}
      float ev4[4] = {e4.x, e4.y, e4.z, e4.w};
      float wv8[8] = {wa.x, wa.y, wa.z, wa.w, wb.x, wb.y, wb.z, wb.w};
#pragma unroll
      for (int ri = 0; ri < 4; ++ri)
#pragma unroll
        for (int ci = 0; ci < 8; ++ci)
          y[ri][ci] = fmaf(ev4[ri], wv8[ci], y[ri][ci]);
    }
    // bias
    const float* bias = isT1 ? b1 : b2;
    float bv[8];
#pragma unroll
    for (int ci = 0; ci < 8; ++ci) bv[ci] = bias[ci * 8 + cg];
#pragma unroll
    for (int ri = 0; ri < 4; ++ri)
#pragma unroll
      for (int ci = 0; ci < 8; ++ci)
        y[ri][ci] = __fadd_rn(y[ri][ci], bv[ci]);
    // per-row ss butterfly-replica + normalize + store
    float* dstB = isT1 ? T1 : T2c;
#pragma unroll
    for (int ri = 0; ri < 4; ++ri) {
      float A0 = __fadd_rn(__fmul_rn(y[ri][0], y[ri][0]),
                           __fmul_rn(y[ri][4], y[ri][4]));
      float A1 = __fadd_rn(__fmul_rn(y[ri][1], y[ri][1]),
                           __fmul_rn(y[ri][5], y[ri][5]));
      float A2 = __fadd_rn(__fmul_rn(y[ri][2], y[ri][2]),
                           __fmul_rn(y[ri][6], y[ri][6]));
      float A3 = __fadd_rn(__fmul_rn(y[ri][3], y[ri][3]),
                           __fmul_rn(y[ri][7], y[ri][7]));
      float B0 = __fadd_rn(A0, A2), B1 = __fadd_rn(A1, A3);
      float C = __fadd_rn(B0, B1);
      C = __fadd_rn(C, __shfl_xor(C, 4));
      C = __fadd_rn(C, __shfl_xor(C, 2));
      C = __fadd_rn(C, __shfl_xor(C, 1));
      float denom = fmaxf(sqrtf(C), EPS_NORM);
      float* drow = dstB + (size_t)(rbase + rg * 4 + ri) * 64;
#pragma unroll
      for (int ci = 0; ci < 8; ++ci) drow[ci * 8 + cg] = y[ri][ci] / denom;
    }
  } else {  // -------- init role: kg -> out0(float) + wkg2(int) --------
    const int4* kg4 = reinterpret_cast<const int4*>(kg);
    float4* o4 = reinterpret_cast<float4*>(out0);
    int4* w4 = reinterpret_cast<int4*>(wkg2);
    for (int i = (blk - 1613) * 256 + tid; i < 800000; i += 200 * 256) {
      int4 v = kg4[i];
      o4[i] = make_float4((float)v.x, (float)v.y, (float)v.z, (float)v.w);
      w4[i] = v;
    }
  }
}

// ================= fallback-path kernels (unchanged) =========================
__global__ __launch_bounds__(256) void k_init(const int* __restrict__ kg,
                                              float* __restrict__ out0,
                                              int* __restrict__ wkg2, int n) {
  int i = blockIdx.x * 256 + threadIdx.x;
  if (i < n) { int v = kg[i]; out0[i] = (float)v; wkg2[i] = v; }
}

__device__ __forceinline__ void transform_row(const float4* __restrict__ Er,
                                              const float* __restrict__ W,
                                              const float* __restrict__ bias,
                                              float (&yn)[64]) {
  float y[64];
#pragma unroll
  for (int j = 0; j < 64; ++j) y[j] = 0.f;
  float4 c0 = Er[0], c1 = Er[1], c2 = Er[2], c3 = Er[3];
#pragma unroll 1
  for (int cc = 0; cc < 4; ++cc) {
    float4 n0, n1, n2, n3;
    if (cc < 3) { n0 = Er[cc * 4 + 4]; n1 = Er[cc * 4 + 5];
                  n2 = Er[cc * 4 + 6]; n3 = Er[cc * 4 + 7]; }
    float ev[16] = {c0.x, c0.y, c0.z, c0.w, c1.x, c1.y, c1.z, c1.w,
                    c2.x, c2.y, c2.z, c2.w, c3.x, c3.y, c3.z, c3.w};
#pragma unroll
    for (int k2i = 0; k2i < 16; ++k2i) {
      const float4* Wr = reinterpret_cast<const float4*>(
          W + ((size_t)(cc * 16 + k2i)) * 64);
      float ek = ev[k2i];
#pragma unroll
      for (int j4 = 0; j4 < 16; ++j4) {
        float4 w = Wr[j4];
        y[j4 * 4 + 0] = fmaf(ek, w.x, y[j4 * 4 + 0]);
        y[j4 * 4 + 1] = fmaf(ek, w.y, y[j4 * 4 + 1]);
        y[j4 * 4 + 2] = fmaf(ek, w.z, y[j4 * 4 + 2]);
        y[j4 * 4 + 3] = fmaf(ek, w.w, y[j4 * 4 + 3]);
      }
    }
    c0 = n0; c1 = n1; c2 = n2; c3 = n3;
  }
  const float4* B4 = reinterpret_cast<const float4*>(bias);
#pragma unroll
  for (int j4 = 0; j4 < 16; ++j4) {
    float4 bb = B4[j4];
    float bv[4] = {bb.x, bb.y, bb.z, bb.w};
#pragma unroll
    for (int t = 0; t < 4; ++t) y[j4 * 4 + t] = __fadd_rn(y[j4 * 4 + t], bv[t]);
  }
  float S1[32];
#pragma unroll
  for (int i = 0; i < 32; ++i)
    S1[i] = __fadd_rn(__fmul_rn(y[i], y[i]), __fmul_rn(y[i + 32], y[i + 32]));
#pragma unroll
  for (int i = 0; i < 16; ++i) S1[i] = __fadd_rn(S1[i], S1[i + 16]);
#pragma unroll
  for (int i = 0; i < 8; ++i)  S1[i] = __fadd_rn(S1[i], S1[i + 8]);
#pragma unroll
  for (int i = 0; i < 4; ++i)  S1[i] = __fadd_rn(S1[i], S1[i + 4]);
#pragma unroll
  for (int i = 0; i < 2; ++i)  S1[i] = __fadd_rn(S1[i], S1[i + 2]);
  float ss = __fadd_rn(S1[0], S1[1]);
  float denom = fmaxf(sqrtf(ss), EPS_NORM);
#pragma unroll
  for (int j = 0; j < 64; ++j) yn[j] = y[j] / denom;
}

__global__ __launch_bounds__(256) void k_transform64(
    const float* __restrict__ src, const int* __restrict__ gidx,
    const float* __restrict__ W, const float* __restrict__ bias,
    float* __restrict__ out, int nrows) {
  __shared__ float Wl[4096];
  for (int i = threadIdx.x; i < 4096; i += 256) Wl[i] = W[i];
  __syncthreads();
  int wid = threadIdx.x >> 6, lane = threadIdx.x & 63;
  int row = rfl(blockIdx.x * 4 + wid);
  if (row >= nrows) return;
  int srow = rfl(gidx ? gidx[row] : row);
  const float* er = src + (size_t)srow * 64;
  float y = 0.f;
#pragma unroll
  for (int k = 0; k < 64; ++k) y = fmaf(er[k], Wl[k * 64 + lane], y);
  y += bias[lane];
  float ss = y * y;
#pragma unroll
  for (int off = 32; off; off >>= 1) ss += __shfl_xor(ss, off);
  float yn = y / fmaxf(sqrtf(ss), EPS_NORM);
  out[(size_t)row * 64 + lane] = yn;
}

__global__ __launch_bounds__(256) void k_ui(
    const float* __restrict__ U, const int* __restrict__ users,
    const float* __restrict__ Iemb, const float* __restrict__ W,
    const float* __restrict__ bias, float* __restrict__ out, int B) {
  __shared__ float Wl[8192];
  for (int i = threadIdx.x; i < 8192; i += 256) Wl[i] = W[i];
  __syncthreads();
  int wid = threadIdx.x >> 6, lane = threadIdx.x & 63;
  int b = rfl(blockIdx.x * 4 + wid);
  if (b >= B) return;
  int usr = rfl(users[b]);
  const float* ur = U + (size_t)usr * 64;
  const float* ir = Iemb + (size_t)b * 64;
  float y = 0.f;
#pragma unroll
  for (int k = 0; k < 64; ++k) y = fmaf(ur[k], Wl[k * 64 + lane], y);
#pragma unroll
  for (int k = 0; k < 64; ++k) y = fmaf(ir[k], Wl[(64 + k) * 64 + lane], y);
  y += bias[lane];
  float ss = y * y;
#pragma unroll
  for (int off = 32; off; off >>= 1) ss += __shfl_xor(ss, off);
  float yn = y / fmaxf(sqrtf(ss), EPS_NORM);
  out[(size_t)b * 64 + lane] = yn;
}

// ------------------ step1 tail (softmax + top4), shared ----------------------
__device__ __forceinline__ void score1_tail(
    float s, int lane, int b, int item, int nb,
    const int* __restrict__ nrel,
    float* __restrict__ out0, float* __restrict__ ap1_out,
    int* __restrict__ s1_idx, int* __restrict__ s1_rel, int* __restrict__ s1_ent,
    float* __restrict__ lmp1) {
  float m = s;
#pragma unroll
  for (int off = 32; off; off >>= 1) m = fmaxf(m, __shfl_xor(m, off));
  float ex = expf(s - m);
  float sum = ex;
#pragma unroll
  for (int off = 32; off; off >>= 1) sum += __shfl_xor(sum, off);
  float p = ex / sum;
  int rank = 0;
  for (int k2 = 0; k2 < 64; ++k2) {
    float pv = __shfl(p, k2);
    rank += (pv > p || (pv == p && k2 < lane)) ? 1 : 0;
  }
  float acc = 0.f;
#pragma unroll
  for (int rr = 0; rr < 4; ++rr) {
    unsigned long long msk = __ballot(rank == rr);
    int src = __ffsll(msk) - 1;
    acc += __shfl(p, src);
  }
  float lm = logf(acc * 0.25f);
  if (lane == 0) { ap1_out[b] = lm; lmp1[b] = lm; }
  if (rank < 4) {
    s1_idx[b * 4 + rank] = lane;
    s1_ent[b * 4 + rank] = nb;
    s1_rel[b * 4 + rank] = nrel[(size_t)item * 64 + lane];
    out0[(size_t)item * 64 + lane] = 0.0f;
  }
}

// ---------- step1 (path A): gather T1 rows + in-register dot + tail ----------
__global__ __launch_bounds__(256) void k_score1g(
    const int* __restrict__ items, const int* __restrict__ kg,
    const int* __restrict__ nrel, const float* __restrict__ T1,
    const float* __restrict__ uiE,
    float* __restrict__ out0, float* __restrict__ ap1_out,
    int* __restrict__ s1_idx, int* __restrict__ s1_rel, int* __restrict__ s1_ent,
    float* __restrict__ lmp1) {
  int tid = threadIdx.x, wv = tid >> 6, lane = tid & 63;
  int b = rfl(blockIdx.x * 4 + wv);
  int item = rfl(items[b]);
  int nb = kg[(size_t)item * 64 + lane];
  const float4* R = reinterpret_cast<const float4*>(T1 + (size_t)nb * 64);
  float yn[64];
#pragma unroll
  for (int j4 = 0; j4 < 16; ++j4) {
    float4 v = R[j4];
    yn[4 * j4] = v.x; yn[4 * j4 + 1] = v.y; yn[4 * j4 + 2] = v.z; yn[4 * j4 + 3] = v.w;
  }
  const float4* Ur = reinterpret_cast<const float4*>(uiE + (size_t)b * 64);
  float D[32];
#pragma unroll
  for (int i4 = 0; i4 < 8; ++i4) {
    float4 ua = Ur[i4], ub = Ur[i4 + 8];
    float uav[4] = {ua.x, ua.y, ua.z, ua.w};
    float ubv[4] = {ub.x, ub.y, ub.z, ub.w};
#pragma unroll
    for (int t = 0; t < 4; ++t) {
      int i = i4 * 4 + t;
      D[i] = __fadd_rn(__fmul_rn(yn[i], uav[t]), __fmul_rn(yn[i + 32], ubv[t]));
    }
  }
#pragma unroll
  for (int i = 0; i < 16; ++i) D[i] = __fadd_rn(D[i], D[i + 16]);
#pragma unroll
  for (int i = 0; i < 8; ++i)  D[i] = __fadd_rn(D[i], D[i + 8]);
#pragma unroll
  for (int i = 0; i < 4; ++i)  D[i] = __fadd_rn(D[i], D[i + 4]);
#pragma unroll
  for (int i = 0; i < 2; ++i)  D[i] = __fadd_rn(D[i], D[i + 2]);
  float s = __fadd_rn(D[0], D[1]);
  score1_tail(s, lane, b, item, nb, nrel, out0, ap1_out, s1_idx, s1_rel, s1_ent, lmp1);
}

// ---------- step1 (path B fallback): fused transform + dot + tail ------------
__global__ __launch_bounds__(256) void k_score1(
    const int* __restrict__ items, const int* __restrict__ kg,
    const int* __restrict__ nrel, const float* __restrict__ E,
    const float* __restrict__ W1, const float* __restrict__ b1,
    const float* __restrict__ uiE,
    float* __restrict__ out0, float* __restrict__ ap1_out,
    int* __restrict__ s1_idx, int* __restrict__ s1_rel, int* __restrict__ s1_ent,
    float* __restrict__ lmp1) {
  int tid = threadIdx.x, wv = tid >> 6, lane = tid & 63;
  int b = rfl(blockIdx.x * 4 + wv);
  int item = rfl(items[b]);
  int nb = kg[(size_t)item * 64 + lane];
  const float4* Er = reinterpret_cast<const float4*>(E + (size_t)nb * 64);
  float yn[64];
  transform_row(Er, W1, b1, yn);
  const float4* Ur = reinterpret_cast<const float4*>(uiE + (size_t)b * 64);
  float D[32];
#pragma unroll
  for (int i4 = 0; i4 < 8; ++i4) {
    float4 ua = Ur[i4], ub = Ur[i4 + 8];
    float uav[4] = {ua.x, ua.y, ua.z, ua.w};
    float ubv[4] = {ub.x, ub.y, ub.z, ub.w};
#pragma unroll
    for (int t = 0; t < 4; ++t) {
      int i = i4 * 4 + t;
      D[i] = __fadd_rn(__fmul_rn(yn[i], uav[t]), __fmul_rn(yn[i + 32], ubv[t]));
    }
  }
#pragma unroll
  for (int i = 0; i < 16; ++i) D[i] = __fadd_rn(D[i], D[i + 16]);
#pragma unroll
  for (int i = 0; i < 8; ++i)  D[i] = __fadd_rn(D[i], D[i + 8]);
#pragma unroll
  for (int i = 0; i < 4; ++i)  D[i] = __fadd_rn(D[i], D[i + 4]);
#pragma unroll
  for (int i = 0; i < 2; ++i)  D[i] = __fadd_rn(D[i], D[i + 2]);
  float s = __fadd_rn(D[0], D[1]);
  score1_tail(s, lane, b, item, nb, nrel, out0, ap1_out, s1_idx, s1_rel, s1_ent, lmp1);
}

// ------- step2a (path A): compact Eg rows (L2-resident) + stable top-32 ------
__global__ __launch_bounds__(256) void k_score2e(
    const int* __restrict__ users, const int* __restrict__ s1_rel,
    const float* __restrict__ U, const float* __restrict__ Eg,
    const int* __restrict__ allc, int* __restrict__ kept, int N) {
  int wid = threadIdx.x >> 6, lane = threadIdx.x & 63;
  int n = rfl(blockIdx.x * 4 + wid);
  if (n >= N) return;
  int b = n >> 2;
  int rel = rfl(s1_rel[n]);
  int usr = rfl(users[b]);
  int ent = allc[rel * 64 + lane];
  const float* ur = U + (size_t)usr * 64;
  const float4* e4 = reinterpret_cast<const float4*>(Eg + ((size_t)rel * 64 + lane) * 64);
  float s = 0.f;
#pragma unroll
  for (int j4 = 0; j4 < 16; ++j4) {
    float4 t = e4[j4];
    s = fmaf(ur[4 * j4 + 0], t.x, s);
    s = fmaf(ur[4 * j4 + 1], t.y, s);
    s = fmaf(ur[4 * j4 + 2], t.z, s);
    s = fmaf(ur[4 * j4 + 3], t.w, s);
  }
  int rank = 0;
  for (int k2 = 0; k2 < 64; ++k2) {
    float sv = __shfl(s, k2);
    rank += (sv > s || (sv == s && k2 < lane)) ? 1 : 0;
  }
  if (rank < 32) kept[n * 32 + rank] = (lane << 18) | ent;
}

// ------- step2a (path B fallback): scattered E ------------------------------
__global__ __launch_bounds__(256) void k_score2(
    const int* __restrict__ users, const int* __restrict__ s1_rel,
    const float* __restrict__ U, const float* __restrict__ E,
    const int* __restrict__ allc, int* __restrict__ kept, int N) {
  int wid = threadIdx.x >> 6, lane = threadIdx.x & 63;
  int n = rfl(blockIdx.x * 4 + wid);
  if (n >= N) return;
  int b = n >> 2;
  int rel = rfl(s1_rel[n]);
  int usr = rfl(users[b]);
  int ent = allc[rel * 64 + lane];
  const float* ur = U + (size_t)usr * 64;
  const float4* e4 = reinterpret_cast<const float4*>(E + (size_t)ent * 64);
  float s = 0.f;
#pragma unroll
  for (int j4 = 0; j4 < 16; ++j4) {
    float4 t = e4[j4];
    s = fmaf(ur[4 * j4 + 0], t.x, s);
    s = fmaf(ur[4 * j4 + 1], t.y, s);
    s = fmaf(ur[4 * j4 + 2], t.z, s);
    s = fmaf(ur[4 * j4 + 3], t.w, s);
  }
  int rank = 0;
  for (int k2 = 0; k2 < 64; ++k2) {
    float sv = __shfl(s, k2);
    rank += (sv > s || (sv == s && k2 < lane)) ? 1 : 0;
  }
  if (rank < 32) kept[n * 32 + rank] = (lane << 18) | ent;
}

// ------- step2b shared body: s2, log_softmax, gumbel sample, scatter ---------
__device__ __forceinline__ void sample_body(
    float q, int n, int b, int lane,
    const int* __restrict__ items, const int* __restrict__ s1_idx,
    int rel, const float* __restrict__ T2c, const int* __restrict__ kept,
    float* __restrict__ p2, int* __restrict__ wkg2) {
  int m = lane & 31;
  int pk = kept[n * 32 + m];
  int c = pk >> 18;
  int ent = pk & 0x3FFFF;
  const float4* c4 = reinterpret_cast<const float4*>(T2c + ((size_t)rel * 64 + c) * 64);
  float s = 0.f;
#pragma unroll
  for (int j4 = 0; j4 < 16; ++j4) {
    float4 t = c4[j4];
    s = fmaf(__shfl(q, 4 * j4 + 0), t.x, s);
    s = fmaf(__shfl(q, 4 * j4 + 1), t.y, s);
    s = fmaf(__shfl(q, 4 * j4 + 2), t.z, s);
    s = fmaf(__shfl(q, 4 * j4 + 3), t.w, s);
  }
  float mx = s;
#pragma unroll
  for (int off = 1; off < 32; off <<= 1) mx = fmaxf(mx, __shfl_xor(mx, off));
  float shv = s - mx;
  float se = expf(shv);
  float sum = se;
#pragma unroll
  for (int off = 1; off < 32; off <<= 1) sum += __shfl_xor(sum, off);
  float logp = shv - logf(sum);
  uint32_t h0, h1;
  threefry2x32(0u, 42u, 0u, (uint32_t)(n * 32 + m), h0, h1);
  uint32_t bits = h0 ^ h1;
  float u0 = __uint_as_float((bits >> 9) | 0x3F800000u) - 1.0f;
  float uu = fmaxf(u0, F32_TINY);
  float g = -logf(-logf(uu));
  float z = g + logp;
  float bz = z; int bm = m;
#pragma unroll
  for (int off = 1; off < 32; off <<= 1) {
    float oz = __shfl_xor(bz, off);
    int om = __shfl_xor(bm, off);
    if (oz > bz || (oz == bz && om < bm)) { bz = oz; bm = om; }
  }
  if (lane == bm) {
    p2[n] = expf(logp);
    int col = s1_idx[n];
    int item = items[b];
    atomicMax(&wkg2[(size_t)item * 64 + col], ((b + 1) << 18) | ent);
  }
}

// ---------- step2b (path A): T1-row read, no transform -----------------------
__global__ __launch_bounds__(256) void k_sample2(
    const int* __restrict__ items,
    const int* __restrict__ s1_idx, const int* __restrict__ s1_rel,
    const int* __restrict__ s1_ent, const float* __restrict__ T1,
    const float* __restrict__ T2c, const float* __restrict__ uiE,
    const int* __restrict__ kept,
    float* __restrict__ p2, int* __restrict__ wkg2, int N) {
  int tid = threadIdx.x, wid = tid >> 6, lane = tid & 63;
  int n = rfl(blockIdx.x * 4 + wid);
  if (n >= N) return;
  int b = n >> 2;
  int rel = rfl(s1_rel[n]);
  int repl = rfl(s1_ent[n]);
  float q = uiE[(size_t)b * 64 + lane] * T1[(size_t)repl * 64 + lane];
  sample_body(q, n, b, lane, items, s1_idx, rel, T2c, kept, p2, wkg2);
}

// ---------- step2b (path B fallback): recompute transform --------------------
__global__ __launch_bounds__(256) void k_sample(
    const int* __restrict__ items,
    const int* __restrict__ s1_idx, const int* __restrict__ s1_rel,
    const int* __restrict__ s1_ent,
    const float* __restrict__ E, const float* __restrict__ W1,
    const float* __restrict__ b1, const float* __restrict__ T2c,
    const float* __restrict__ uiE, const int* __restrict__ kept,
    float* __restrict__ p2, int* __restrict__ wkg2, int N) {
  __shared__ float Wl[4096];
  int tid = threadIdx.x;
  for (int i = tid; i < 4096; i += 256) Wl[i] = W1[i];
  __syncthreads();
  int wid = tid >> 6, lane = tid & 63;
  int n = rfl(blockIdx.x * 4 + wid);
  if (n >= N) return;
  int b = n >> 2;
  int rel = rfl(s1_rel[n]);
  int repl = rfl(s1_ent[n]);
  const float* er = E + (size_t)repl * 64;
  float y = 0.f;
#pragma unroll
  for (int k2 = 0; k2 < 64; ++k2) y = fmaf(er[k2], Wl[k2 * 64 + lane], y);
  y += b1[lane];
  float ss = y * y;
#pragma unroll
  for (int off = 32; off; off >>= 1) ss += __shfl_xor(ss, off);
  float yn = y / fmaxf(sqrtf(ss), EPS_NORM);
  float q = uiE[(size_t)b * 64 + lane] * yn;
  sample_body(q, n, b, lane, items, s1_idx, rel, T2c, kept, p2, wkg2);
}

// ---------------- finalize cf_kg2 and ap2 (merged) ---------------------------
__global__ __launch_bounds__(256) void k_fin(const int* __restrict__ wkg2,
                                             const float* __restrict__ p2,
                                             const float* __restrict__ lmp1,
                                             float* __restrict__ out2,
                                             float* __restrict__ out3,
                                             int n, int B) {
  int i = blockIdx.x * 256 + threadIdx.x;
  if (i < n) out2[i] = (float)(wkg2[i] & 0x3FFFF);
  if (i < B) {
    float a = ((p2[i * 4] + p2[i * 4 + 1]) + p2[i * 4 + 2]) + p2[i * 4 + 3];
    out3[i] = lmp1[i] + logf(a * 0.25f);
  }
}

// -----------------------------------------------------------------------------
extern "C" void kernel_launch(void* const* d_in, const int* in_sizes, int n_in,
                              void* d_out, int out_size, void* d_ws, size_t ws_size,
                              hipStream_t stream) {
  const int*   users = (const int*)d_in[0];
  const int*   items = (const int*)d_in[1];
  const int*   kg    = (const int*)d_in[2];
  const int*   allc  = (const int*)d_in[3];
  const int*   nrel  = (const int*)d_in[4];
  const float* U     = (const float*)d_in[5];
  const float* E     = (const float*)d_in[6];
  const float* Iemb  = (const float*)d_in[7];
  const float* uiW   = (const float*)d_in[8];
  const float* uib   = (const float*)d_in[9];
  const float* e1W   = (const float*)d_in[10];
  const float* e1b   = (const float*)d_in[11];
  const float* e2W   = (const float*)d_in[12];
  const float* e2b   = (const float*)d_in[13];

  const int B = 4096, NCELL = 3200000, NCAND = 6400, NR4 = 16384, NENT = 200000;

  float* out0    = (float*)d_out;        // cf_kg1 [3.2M]
  float* out_ap1 = out0 + NCELL;         // ap1    [4096]
  float* out2    = out_ap1 + B;          // cf_kg2 [3.2M]
  float* out_ap2 = out2 + NCELL;         // ap2    [4096]

  float* T2c  = (float*)d_ws;            // 409,600 f
  float* uiE  = T2c + 409600;            // 262,144 f
  int*   wkg2 = (int*)(uiE + 262144);    // 3,200,000 i
  int*   s1i  = wkg2 + NCELL;            // 16384
  int*   s1r  = s1i + NR4;               // 16384
  int*   s1e  = s1r + NR4;               // 16384
  int*   kept = s1e + NR4;               // 524,288
  float* p2   = (float*)(kept + 524288); // 16384
  float* lmp1 = p2 + NR4;                // 4096
  float* T1   = lmp1 + B;                // 12,800,000 f (51.2 MB), path A only
  float* Eg   = out2;                    // raw cand rows, scratch in out2 region
                                         // (k_fin overwrites out2 afterwards)
  const size_t WS_NEED = ((size_t)(T1 + (size_t)NENT * 64) - (size_t)d_ws);
  const bool pathA = ws_size >= WS_NEED;

  if (pathA) {
    // phase1: T1 (1563 blks) + T2c/Eg (50) + init (200) = 1813 blocks
    k_phase1<<<1813, 256, 0, stream>>>(E, allc, e1W, e1b, e2W, e2b, kg,
                                       T1, T2c, Eg, out0, wkg2);
    k_ui<<<(B + 3) / 4, 256, 0, stream>>>(U, users, Iemb, uiW, uib, uiE, B);
    k_score1g<<<B / 4, 256, 0, stream>>>(items, kg, nrel, T1, uiE,
                                         out0, out_ap1, s1i, s1r, s1e, lmp1);
    k_score2e<<<(NR4 + 3) / 4, 256, 0, stream>>>(users, s1r, U, Eg, allc, kept, NR4);
    k_sample2<<<(NR4 + 3) / 4, 256, 0, stream>>>(items, s1i, s1r, s1e, T1, T2c,
                                                 uiE, kept, p2, wkg2, NR4);
  } else {
    k_init<<<(NCELL + 255) / 256, 256, 0, stream>>>(kg, out0, wkg2, NCELL);
    k_ui<<<(B + 3) / 4, 256, 0, stream>>>(U, users, Iemb, uiW, uib, uiE, B);
    k_transform64<<<(NCAND + 3) / 4, 256, 0, stream>>>(E, allc, e2W, e2b, T2c, NCAND);
    k_score1<<<B / 4, 256, 0, stream>>>(items, kg, nrel, E, e1W, e1b, uiE,
                                        out0, out_ap1, s1i, s1r, s1e, lmp1);
    k_score2<<<(NR4 + 3) / 4, 256, 0, stream>>>(users, s1r, U, E, allc, kept, NR4);
    k_sample<<<(NR4 + 3) / 4, 256, 0, stream>>>(items, s1i, s1r, s1e, E, e1W, e1b,
                                                T2c, uiE, kept, p2, wkg2, NR4);
  }
  k_fin<<<(NCELL + 255) / 256, 256, 0, stream>>>(wkg2, p2, lmp1, out2, out_ap2,
                                                 NCELL, B);
}